// Round 6
// baseline (537.323 us; speedup 1.0000x reference)
//
#include <hip/hip_runtime.h>

#define NW 14
#define NL 3
#define NGAT 42            // 3 layers x 14 rotation gates
#define DIM 16384          // 2^14 amplitudes
#define BLOCK 1024
#define NBATCH 12          // 3 layers x batches of (4,4,4,2) gates

// ---------------------------------------------------------------------------
// CNOTs are linear over GF(2): fold them into per-gate masks (R = rows of L,
// C = cols of L^-1). Register blocking: each thread owns a 16-element coset
// of span(batch basis); gate j pairs slots e <-> e^(1<<j).
// Duality: parity(C[p_k] & R[p_j]) = delta_jk, so shifting the coset rep by
// combo[d] (d_j = parity(rep & r_j)) makes slot e's logical bit = bit j of e
// for EVERY thread -> butterflies are static, no runtime selects.
//
// Round 6: amplitudes are 16 NAMED float2 locals (macro codegen, no arrays),
// addresses recomputed inline (srep ^ const). Rounds 3-5 showed the compiler
// pinning 64 VGPRs and dumping amp[16]/adr[16] to scratch (~650 MB HBM write
// traffic/dispatch) regardless of __launch_bounds__/waves_per_eu. This
// version's peak live state (~50 VGPR) fits under 64, and named locals
// cannot be demoted to scratch by a failed SROA.
// ---------------------------------------------------------------------------

constexpr unsigned sigma(unsigned x) { return (x ^ (x >> 5) ^ (x >> 10)) & (DIM - 1); }

constexpr int parity14(int v) { int p = 0; for (int i = 0; i < NW; ++i) p ^= (v >> i) & 1; return p; }
constexpr int hibit(int v) { int h = -1; for (int i = 0; i < NW; ++i) if ((v >> i) & 1) h = i; return h; }

struct Gate {
    int gidx;        // index into gm LDS array (l*14 + w)
    unsigned tpar;   // tid-bit mask: d_j = popc(tid & tpar) & 1 = parity(rep & r_j)
};
struct Batch {
    int ngates;
    Gate g[4];
    unsigned scomboB[16];  // sigma(combo[e]) * 8   (LDS byte offsets)
    unsigned srepcB[10];   // sigma(1<<npp[k]) * 8  (per-tid-bit deposit constants)
};
struct Plan {
    Batch b[NBATCH];
    unsigned ztid[NW];  // tid parity mask for wire w's final Z sign (last batch)
    unsigned zpm[NW];   // bit e: parity(combo_last[e] & zr_w); linear in index
};

constexpr Plan make_plan() {
    Plan P{};
    int R[NW] = {}, C[NW] = {};
    for (int p = 0; p < NW; ++p) { R[p] = 1 << p; C[p] = 1 << p; }
    int bi = 0;
    int lastNpp[10] = {}; int lastCombo[16] = {};
    for (int l = 0; l < NL; ++l) {
        const int sizes[4] = {4, 4, 4, 2};
        int w0 = 0;
        for (int s = 0; s < 4; ++s) {
            Batch& B = P.b[bi];
            int ng = sizes[s];
            B.ngates = ng;
            int basis[4] = {}, rr[4] = {};
            for (int j = 0; j < ng; ++j) {
                int w = w0 + j, p = 13 - w;
                basis[j] = C[p];
                rr[j] = R[p];
                B.g[j].gidx = l * NW + w;
            }
            // running echelon for independence checks
            int ech[4] = {}; int ne = 0;
            for (int j = 0; j < ng; ++j) {
                int v = basis[j];
                bool ch = true;
                while (ch) { ch = false;
                    for (int k = 0; k < ne; ++k)
                        if (v && ((v >> hibit(ech[k])) & 1)) { v ^= ech[k]; ch = true; }
                }
                ech[ne++] = v;
            }
            // pad to 4 basis vectors from the null space of the gate parity
            // masks (so padded slots never flip a gate's logical bit)
            int nb = ng;
            for (int cand = 1; cand < DIM && nb < 4; ++cand) {
                bool ok = true;
                for (int j = 0; j < ng; ++j) if (parity14(cand & rr[j])) { ok = false; break; }
                if (!ok) continue;
                int v = cand;
                bool ch = true;
                while (ch) { ch = false;
                    for (int k = 0; k < ne; ++k)
                        if (v && ((v >> hibit(ech[k])) & 1)) { v ^= ech[k]; ch = true; }
                }
                if (v) { basis[nb++] = cand; ech[ne++] = v; }
            }
            // pivots & non-pivot deposit positions
            int piv[4] = {};
            for (int k = 0; k < 4; ++k) piv[k] = hibit(ech[k]);
            for (int a = 0; a < 4; ++a)
                for (int b2 = a + 1; b2 < 4; ++b2)
                    if (piv[b2] < piv[a]) { int t = piv[a]; piv[a] = piv[b2]; piv[b2] = t; }
            int npp[10] = {}; int nn = 0;
            for (int bit = 0; bit < NW; ++bit) {
                bool isp = false;
                for (int k = 0; k < 4; ++k) if (piv[k] == bit) isp = true;
                if (!isp) npp[nn++] = bit;
            }
            // coset offsets (sigma is GF(2)-linear)
            int combo[16] = {};
            for (int e = 0; e < 16; ++e) {
                int v = 0;
                for (int j = 0; j < 4; ++j) if ((e >> j) & 1) v ^= basis[j];
                combo[e] = v;
                B.scomboB[e] = sigma((unsigned)v) * 8u;
            }
            for (int k = 0; k < 10; ++k) B.srepcB[k] = sigma(1u << npp[k]) * 8u;
            for (int j = 0; j < ng; ++j) {
                unsigned tp = 0;
                for (int k = 0; k < 10; ++k) tp |= (unsigned)((rr[j] >> npp[k]) & 1) << k;
                B.g[j].tpar = tp;
            }
            if (bi == NBATCH - 1) {
                for (int k = 0; k < 10; ++k) lastNpp[k] = npp[k];
                for (int e = 0; e < 16; ++e) lastCombo[e] = combo[e];
            }
            w0 += ng;
            ++bi;
        }
        // CNOT chain (w,w+1) w=0..12 then (13,0): L <- sigma o L
        for (int w = 0; w < NW; ++w) {
            int c = w, t = (w + 1) % NW;
            int pc = 13 - c, pt = 13 - t;
            R[pt] ^= R[pc];
            C[pc] ^= C[pt];
        }
    }
    for (int w = 0; w < NW; ++w) {
        int zrw = R[13 - w];
        unsigned tz = 0, zp = 0;
        for (int k = 0; k < 10; ++k) tz |= (unsigned)((zrw >> lastNpp[k]) & 1) << k;
        for (int e = 0; e < 16; ++e) zp |= (unsigned)parity14(lastCombo[e] & zrw) << e;
        P.ztid[w] = tz; P.zpm[w] = zp;
    }
    return P;
}

constexpr Plan PLAN = make_plan();

__device__ __forceinline__ unsigned sigma_rt(unsigned x) { return x ^ (x >> 5) ^ (x >> 10); }

// ---- macro codegen: named float2 locals, inline addresses, static pairs ----
#define LDE(e) float2 a##e = *(const float2*)(lds + (srep ^ B.scomboB[e]));
#define STE(e) *(float2*)(lds + (srep ^ B.scomboB[e])) = a##e;
#define PRE(e) a##e.x = a##e.x * a##e.x + a##e.y * a##e.y;
#define ACW(e) acc += a##e.x * (((PLAN.zpm[w] >> (e)) & 1u) ? -sw : sw);

#define BF(A, B_) { const float2 t0 = A, t1 = B_; \
    A.x  = u0.x * t0.x - u0.y * t0.y + u0.z * t1.x - u0.w * t1.y; \
    A.y  = u0.x * t0.y + u0.y * t0.x + u0.z * t1.y + u0.w * t1.x; \
    B_.x = u1.x * t0.x - u1.y * t0.y + u1.z * t1.x - u1.w * t1.y; \
    B_.y = u1.x * t0.y + u1.y * t0.x + u1.z * t1.y + u1.w * t1.x; }

#define GATE(J, PAIRS) if constexpr ((J) < B.ngates) { \
    const float4 u0 = *(const float4*)&gm[B.g[J].gidx * 8]; \
    const float4 u1 = *(const float4*)&gm[B.g[J].gidx * 8 + 4]; \
    PAIRS }

template <int BI>
__device__ __forceinline__ void do_batch(char* __restrict__ lds, const float* __restrict__ gm,
                                         unsigned tid, const float* __restrict__ g_hw, float& acc)
{
    constexpr Batch B = PLAN.b[BI];
    __syncthreads();   // previous batch's stores (or initial staging) visible
    unsigned srep = 0;
    #pragma unroll
    for (int k = 0; k < 10; ++k)
        srep ^= (unsigned)(-(int)((tid >> k) & 1u)) & B.srepcB[k];
    // duality correction: shift rep so every gate's logical bit == slot bit
    unsigned d = 0;
    #pragma unroll
    for (int j = 0; j < 4; ++j)
        if (j < B.ngates) {
            const unsigned bj = (unsigned)(__popc(tid & B.g[j].tpar) & 1);
            d |= bj << j;
            srep ^= (unsigned)(-(int)bj) & B.scomboB[1u << j];
        }

    LDE(0)  LDE(1)  LDE(2)  LDE(3)  LDE(4)  LDE(5)  LDE(6)  LDE(7)
    LDE(8)  LDE(9)  LDE(10) LDE(11) LDE(12) LDE(13) LDE(14) LDE(15)

    GATE(0, BF(a0,a1)  BF(a2,a3)   BF(a4,a5)   BF(a6,a7)
            BF(a8,a9)  BF(a10,a11) BF(a12,a13) BF(a14,a15))
    GATE(1, BF(a0,a2)  BF(a1,a3)   BF(a4,a6)   BF(a5,a7)
            BF(a8,a10) BF(a9,a11)  BF(a12,a14) BF(a13,a15))
    GATE(2, BF(a0,a4)  BF(a1,a5)   BF(a2,a6)   BF(a3,a7)
            BF(a8,a12) BF(a9,a13)  BF(a10,a14) BF(a11,a15))
    GATE(3, BF(a0,a8)  BF(a1,a9)   BF(a2,a10)  BF(a3,a11)
            BF(a4,a12) BF(a5,a13)  BF(a6,a14)  BF(a7,a15))

    if constexpr (BI == NBATCH - 1) {
        // epilogue from registers: fold |psi|^2 into .x, then per-wire signs.
        // parity for wire w at slot e: ztid(tid) ^ zpm_bit(d) ^ zpm_bit(e)
        PRE(0)  PRE(1)  PRE(2)  PRE(3)  PRE(4)  PRE(5)  PRE(6)  PRE(7)
        PRE(8)  PRE(9)  PRE(10) PRE(11) PRE(12) PRE(13) PRE(14) PRE(15)
        #pragma unroll
        for (int w = 0; w < NW; ++w) {
            const unsigned pz = ((unsigned)__popc(tid & PLAN.ztid[w]) ^ (PLAN.zpm[w] >> d)) & 1u;
            const float hv = g_hw[w];
            const float sw = pz ? -hv : hv;
            ACW(0)  ACW(1)  ACW(2)  ACW(3)  ACW(4)  ACW(5)  ACW(6)  ACW(7)
            ACW(8)  ACW(9)  ACW(10) ACW(11) ACW(12) ACW(13) ACW(14) ACW(15)
        }
    } else {
        STE(0)  STE(1)  STE(2)  STE(3)  STE(4)  STE(5)  STE(6)  STE(7)
        STE(8)  STE(9)  STE(10) STE(11) STE(12) STE(13) STE(14) STE(15)
    }
}

__attribute__((amdgpu_flat_work_group_size(BLOCK, BLOCK), amdgpu_waves_per_eu(4, 4)))
__global__ void qsim_kernel(
    const float* __restrict__ g_sr, const float* __restrict__ g_si,
    const float* __restrict__ g_params, const float* __restrict__ g_hw,
    const float* __restrict__ g_hb, float* __restrict__ g_out)
{
    extern __shared__ char lds[];                  // DIM * 8 B: float2-interleaved, sigma-swizzled
    __shared__ __align__(16) float gm[NGAT * 8];   // per gate: u00,u01,u10,u11 (complex)
    __shared__ float red[BLOCK / 64];

    const unsigned tid = threadIdx.x;
    const int b = blockIdx.x;
    const float* __restrict__ srcr = g_sr + (size_t)b * DIM;
    const float* __restrict__ srci = g_si + (size_t)b * DIM;

    // ---- gate matrices U = RZ @ RY @ RX, one gate per thread ----
    if (tid < NGAT) {
        const float tx = g_params[tid * 3 + 0];
        const float ty = g_params[tid * 3 + 1];
        const float tz = g_params[tid * 3 + 2];
        const float cx = cosf(0.5f * tx), sx = sinf(0.5f * tx);
        const float cy = cosf(0.5f * ty), sy = sinf(0.5f * ty);
        const float cz = cosf(0.5f * tz), sz = sinf(0.5f * tz);
        const float a00r = cy * cx,  a00i = sy * sx;
        const float a01r = -sy * cx, a01i = -cy * sx;
        const float a10r = sy * cx,  a10i = -cy * sx;
        const float a11r = cy * cx,  a11i = -sy * sx;
        gm[tid * 8 + 0] = cz * a00r + sz * a00i;
        gm[tid * 8 + 1] = cz * a00i - sz * a00r;
        gm[tid * 8 + 2] = cz * a01r + sz * a01i;
        gm[tid * 8 + 3] = cz * a01i - sz * a01r;
        gm[tid * 8 + 4] = cz * a10r - sz * a10i;
        gm[tid * 8 + 5] = cz * a10i + sz * a10r;
        gm[tid * 8 + 6] = cz * a11r - sz * a11i;
        gm[tid * 8 + 7] = cz * a11i + sz * a11r;
    }

    // ---- load state: coalesced float4 global reads -> interleaved swizzled LDS ----
    #pragma unroll
    for (int it = 0; it < 4; ++it) {
        const int x = (int)tid * 4 + it * 4096;
        const float4 re = *(const float4*)(srcr + x);
        const float4 im = *(const float4*)(srci + x);
        ((float2*)lds)[sigma_rt(x + 0)] = make_float2(re.x, im.x);
        ((float2*)lds)[sigma_rt(x + 1)] = make_float2(re.y, im.y);
        ((float2*)lds)[sigma_rt(x + 2)] = make_float2(re.z, im.z);
        ((float2*)lds)[sigma_rt(x + 3)] = make_float2(re.w, im.w);
    }

    float acc = 0.0f;
    do_batch<0>(lds, gm, tid, g_hw, acc);
    do_batch<1>(lds, gm, tid, g_hw, acc);
    do_batch<2>(lds, gm, tid, g_hw, acc);
    do_batch<3>(lds, gm, tid, g_hw, acc);
    do_batch<4>(lds, gm, tid, g_hw, acc);
    do_batch<5>(lds, gm, tid, g_hw, acc);
    do_batch<6>(lds, gm, tid, g_hw, acc);
    do_batch<7>(lds, gm, tid, g_hw, acc);
    do_batch<8>(lds, gm, tid, g_hw, acc);
    do_batch<9>(lds, gm, tid, g_hw, acc);
    do_batch<10>(lds, gm, tid, g_hw, acc);
    do_batch<11>(lds, gm, tid, g_hw, acc);

    // ---- reduce: wave shuffle then cross-wave via LDS ----
    #pragma unroll
    for (int off = 32; off > 0; off >>= 1) acc += __shfl_down(acc, off);
    const int lane = tid & 63, wid = tid >> 6;
    if (lane == 0) red[wid] = acc;
    __syncthreads();
    if (tid == 0) {
        float s = 0.0f;
        #pragma unroll
        for (int k = 0; k < BLOCK / 64; ++k) s += red[k];
        g_out[b] = s + g_hb[0];
    }
}

extern "C" void kernel_launch(void* const* d_in, const int* in_sizes, int n_in,
                              void* d_out, int out_size, void* d_ws, size_t ws_size,
                              hipStream_t stream) {
    const float* sr = (const float*)d_in[0];
    const float* si = (const float*)d_in[1];
    const float* vp = (const float*)d_in[2];
    const float* hw = (const float*)d_in[3];
    const float* hb = (const float*)d_in[4];
    float* out = (float*)d_out;

    dim3 grid(out_size);          // 1024 batch elements, one block each
    dim3 block(BLOCK);
    size_t shmem = (size_t)DIM * sizeof(float2);  // 128 KiB dynamic LDS
    qsim_kernel<<<grid, block, shmem, stream>>>(sr, si, vp, hw, hb, out);
}

// Round 8
// 285.548 us; speedup vs baseline: 1.8817x; 1.8817x over previous
//
#include <hip/hip_runtime.h>

#define NW 14
#define NL 3
#define NGAT 42            // 3 layers x 14 rotation gates
#define DIM 16384          // 2^14 amplitudes
#define BLOCK 1024
#define NBATCH 12          // 3 layers x batches of (4,4,4,2) gates

// ---------------------------------------------------------------------------
// CNOTs are GF(2)-linear on index bits -> folded into per-gate masks
// (R = rows of L, C = cols of L^-1). Each thread owns a 16-element coset of
// span(basis); gate j pairs register slots e <-> e^(1<<j). Duality
// (parity(C_k & R_j) = delta_jk) shifts the coset rep so slot e's logical
// bit == bit j of e for every thread -> butterflies are static.
//
// Inter-batch RELAYOUT (kills the 16 long-lived address regs that caused
// rounds 3-6's scratch spill): batch bi WRITES into the layout batch bi+1
// reads: phys slot of (thread t, slot e) = t*16 ^ e ^ ((t&7)<<1)
//   -> stores: 8 bank-balanced ds_write_b128 at wbase ^ (k<<4)
//   -> reads: 16 scattered ds_read_b64 via Phi_prev = G o F_prev^{-1}
//      (constexpr bit-matrix algebra); addresses die immediately.
//
// ROUND 8 FIX: relayout writes alias OTHER threads' unread read-slots, so a
// second __syncthreads() goes between the gates and the stores (round 7 raced
// -> absmax 1.5e-2). Reads -> gates -> sync -> writes; the state lives in
// the block's registers across the barrier.
// ---------------------------------------------------------------------------

constexpr int parity14(int v) { int p = 0; for (int i = 0; i < NW; ++i) p ^= (v >> i) & 1; return p; }
constexpr int hibit(int v) { int h = -1; for (int i = 0; i < NW; ++i) if ((v >> i) & 1) h = i; return h; }

// linear map over GF(2)^14 as 14 columns
struct Lin { int col[NW]; };

constexpr Lin lin_identity() { Lin M{}; for (int i = 0; i < NW; ++i) M.col[i] = 1 << i; return M; }
constexpr int lin_apply(const Lin& M, int x) {
    int r = 0;
    for (int i = 0; i < NW; ++i) if ((x >> i) & 1) r ^= M.col[i];
    return r;
}
constexpr Lin lin_inverse(const Lin& M) {
    int E[NW] = {}, P[NW] = {};   // echelon vectors by leading bit + preimages
    for (int i = 0; i < NW; ++i) {
        int v = M.col[i], p = 1 << i;
        while (v) {
            int h = hibit(v);
            if (!E[h]) { E[h] = v; P[h] = p; break; }
            v ^= E[h]; p ^= P[h];
        }
    }
    Lin R{};
    for (int i = 0; i < NW; ++i) {
        int v = 1 << i, p = 0;
        while (v) { int h = hibit(v); v ^= E[h]; p ^= P[h]; }
        R.col[i] = p;
    }
    return R;
}
constexpr Lin lin_compose(const Lin& A, const Lin& B) {   // A(B(x))
    Lin R{};
    for (int i = 0; i < NW; ++i) R.col[i] = lin_apply(A, B.col[i]);
    return R;
}

struct Gate {
    int gidx;        // index into gm LDS array (l*14 + w)
    unsigned tpar;   // tid-bit mask: d_j = popc(tid & tpar) & 1
};
struct Batch {
    int ngates;
    Gate g[4];
    unsigned rcB[16];    // byte const: 8 * Phi_prev(combo[e])
    unsigned rtidB[10];  // byte const: 8 * Phi_prev(1<<npp[k])   (deposit)
    unsigned rshiftB[4]; // byte const: 8 * Phi_prev(basis[j])    (duality shift)
};
struct Plan {
    Batch b[NBATCH];
    unsigned ztid[NW];  // tid parity mask for wire w's final Z sign (last batch)
    unsigned zpm[NW];   // bit e: parity(combo_last[e] & zr_w)
};

constexpr Plan make_plan() {
    Plan P{};
    int R[NW] = {}, C[NW] = {};
    for (int p = 0; p < NW; ++p) { R[p] = 1 << p; C[p] = 1 << p; }

    // G: packed (bits 0..3 = e, 4..13 = t) -> phys slot = (t<<4) ^ e ^ ((t&7)<<1)
    Lin G{};
    for (int i = 0; i < 4; ++i) G.col[i] = 1 << i;
    for (int k = 0; k < 10; ++k) G.col[4 + k] = (1 << (4 + k)) ^ (k < 3 ? (1 << (1 + k)) : 0);

    Lin prevPhi = lin_identity();   // staging writes element x at slot x

    int bi = 0;
    int lastNpp[10] = {}; int lastCombo[16] = {};
    for (int l = 0; l < NL; ++l) {
        const int sizes[4] = {4, 4, 4, 2};
        int w0 = 0;
        for (int s = 0; s < 4; ++s) {
            Batch& B = P.b[bi];
            int ng = sizes[s];
            B.ngates = ng;
            int basis[4] = {}, rr[4] = {};
            for (int j = 0; j < ng; ++j) {
                int w = w0 + j, p = 13 - w;
                basis[j] = C[p];
                rr[j] = R[p];
                B.g[j].gidx = l * NW + w;
            }
            // echelon for independence
            int ech[4] = {}; int ne = 0;
            for (int j = 0; j < ng; ++j) {
                int v = basis[j];
                bool ch = true;
                while (ch) { ch = false;
                    for (int k = 0; k < ne; ++k)
                        if (v && ((v >> hibit(ech[k])) & 1)) { v ^= ech[k]; ch = true; }
                }
                ech[ne++] = v;
            }
            // pad to 4 from the null space of the gate parity masks
            int nb = ng;
            for (int cand = 1; cand < DIM && nb < 4; ++cand) {
                bool ok = true;
                for (int j = 0; j < ng; ++j) if (parity14(cand & rr[j])) { ok = false; break; }
                if (!ok) continue;
                int v = cand;
                bool ch = true;
                while (ch) { ch = false;
                    for (int k = 0; k < ne; ++k)
                        if (v && ((v >> hibit(ech[k])) & 1)) { v ^= ech[k]; ch = true; }
                }
                if (v) { basis[nb++] = cand; ech[ne++] = v; }
            }
            // pivots & non-pivot deposit positions
            int piv[4] = {};
            for (int k = 0; k < 4; ++k) piv[k] = hibit(ech[k]);
            for (int a = 0; a < 4; ++a)
                for (int b2 = a + 1; b2 < 4; ++b2)
                    if (piv[b2] < piv[a]) { int t = piv[a]; piv[a] = piv[b2]; piv[b2] = t; }
            int npp[10] = {}; int nn = 0;
            for (int bit = 0; bit < NW; ++bit) {
                bool isp = false;
                for (int k = 0; k < 4; ++k) if (piv[k] == bit) isp = true;
                if (!isp) npp[nn++] = bit;
            }
            int combo[16] = {};
            for (int e = 0; e < 16; ++e) {
                int v = 0;
                for (int j = 0; j < 4; ++j) if ((e >> j) & 1) v ^= basis[j];
                combo[e] = v;
            }
            // duality tid-parity masks
            unsigned tpar[4] = {};
            for (int j = 0; j < ng; ++j) {
                unsigned tp = 0;
                for (int k = 0; k < 10; ++k) tp |= (unsigned)((rr[j] >> npp[k]) & 1) << k;
                B.g[j].tpar = tp;
                tpar[j] = tp;
            }
            // read constants through prevPhi (layout written by previous batch)
            for (int e = 0; e < 16; ++e) B.rcB[e] = (unsigned)lin_apply(prevPhi, combo[e]) * 8u;
            for (int k = 0; k < 10; ++k) B.rtidB[k] = (unsigned)lin_apply(prevPhi, 1 << npp[k]) * 8u;
            for (int j = 0; j < ng; ++j) B.rshiftB[j] = (unsigned)lin_apply(prevPhi, basis[j]) * 8u;

            // this batch's write layout: Phi = G o F^-1,
            // F(packed) = rep(t) ^ combo[e]  (bits 0..3 = e, 4..13 = t)
            Lin F{};
            for (int j = 0; j < 4; ++j) F.col[j] = basis[j];
            for (int k = 0; k < 10; ++k) {
                int c = 1 << npp[k];
                for (int j = 0; j < ng; ++j) if ((tpar[j] >> k) & 1) c ^= basis[j];
                F.col[4 + k] = c;
            }
            prevPhi = lin_compose(G, lin_inverse(F));

            if (bi == NBATCH - 1) {
                for (int k = 0; k < 10; ++k) lastNpp[k] = npp[k];
                for (int e = 0; e < 16; ++e) lastCombo[e] = combo[e];
            }
            w0 += ng;
            ++bi;
        }
        // CNOT chain (w,w+1) w=0..12 then (13,0): L <- sigma o L
        for (int w = 0; w < NW; ++w) {
            int c = w, t = (w + 1) % NW;
            int pc = 13 - c, pt = 13 - t;
            R[pt] ^= R[pc];
            C[pc] ^= C[pt];
        }
    }
    for (int w = 0; w < NW; ++w) {
        int zrw = R[13 - w];
        unsigned tz = 0, zp = 0;
        for (int k = 0; k < 10; ++k) tz |= (unsigned)((zrw >> lastNpp[k]) & 1) << k;
        for (int e = 0; e < 16; ++e) zp |= (unsigned)parity14(lastCombo[e] & zrw) << e;
        P.ztid[w] = tz; P.zpm[w] = zp;
    }
    return P;
}

constexpr Plan PLAN = make_plan();

// ---- macro codegen: named float2 locals, transient addresses ----
#define LDE(e) float2 a##e = *(const float2*)(lds + (srep ^ PLAN.b[BI].rcB[e]));
#define STP(k, A, B_) *(float4*)(lds + (wbase ^ ((k) << 4))) = make_float4(A.x, A.y, B_.x, B_.y);
#define PRE(e) a##e.x = a##e.x * a##e.x + a##e.y * a##e.y;
#define ACW(e) acc += a##e.x * (((PLAN.zpm[w] >> (e)) & 1u) ? -sw : sw);

#define BF(A, B_) { const float2 t0 = A, t1 = B_; \
    A.x  = u0.x * t0.x - u0.y * t0.y + u0.z * t1.x - u0.w * t1.y; \
    A.y  = u0.x * t0.y + u0.y * t0.x + u0.z * t1.y + u0.w * t1.x; \
    B_.x = u1.x * t0.x - u1.y * t0.y + u1.z * t1.x - u1.w * t1.y; \
    B_.y = u1.x * t0.y + u1.y * t0.x + u1.z * t1.y + u1.w * t1.x; }

#define GATE(J, PAIRS) if constexpr ((J) < PLAN.b[BI].ngates) { \
    const float4 u0 = *(const float4*)&gm[PLAN.b[BI].g[J].gidx * 8]; \
    const float4 u1 = *(const float4*)&gm[PLAN.b[BI].g[J].gidx * 8 + 4]; \
    PAIRS }

template <int BI>
__device__ __forceinline__ void do_batch(char* __restrict__ lds, const float* __restrict__ gm,
                                         unsigned tid, const float* __restrict__ g_hw, float& acc)
{
    __syncthreads();   // previous batch's stores (or initial staging) visible
    unsigned srep = 0;
    #pragma unroll
    for (int k = 0; k < 10; ++k)
        srep ^= (unsigned)(-(int)((tid >> k) & 1u)) & PLAN.b[BI].rtidB[k];
    // duality correction: shift rep so every gate's logical bit == slot bit
    unsigned d = 0;
    #pragma unroll
    for (int j = 0; j < 4; ++j)
        if (j < PLAN.b[BI].ngates) {
            const unsigned bj = (unsigned)(__popc(tid & PLAN.b[BI].g[j].tpar) & 1);
            d |= bj << j;
            srep ^= (unsigned)(-(int)bj) & PLAN.b[BI].rshiftB[j];
        }

    LDE(0)  LDE(1)  LDE(2)  LDE(3)  LDE(4)  LDE(5)  LDE(6)  LDE(7)
    LDE(8)  LDE(9)  LDE(10) LDE(11) LDE(12) LDE(13) LDE(14) LDE(15)

    GATE(0, BF(a0,a1)  BF(a2,a3)   BF(a4,a5)   BF(a6,a7)
            BF(a8,a9)  BF(a10,a11) BF(a12,a13) BF(a14,a15))
    GATE(1, BF(a0,a2)  BF(a1,a3)   BF(a4,a6)   BF(a5,a7)
            BF(a8,a10) BF(a9,a11)  BF(a12,a14) BF(a13,a15))
    GATE(2, BF(a0,a4)  BF(a1,a5)   BF(a2,a6)   BF(a3,a7)
            BF(a8,a12) BF(a9,a13)  BF(a10,a14) BF(a11,a15))
    GATE(3, BF(a0,a8)  BF(a1,a9)   BF(a2,a10)  BF(a3,a11)
            BF(a4,a12) BF(a5,a13)  BF(a6,a14)  BF(a7,a15))

    if constexpr (BI == NBATCH - 1) {
        // epilogue from registers; wire-w parity at slot e: ztid(tid)^zpm(d)^zpm(e)
        PRE(0)  PRE(1)  PRE(2)  PRE(3)  PRE(4)  PRE(5)  PRE(6)  PRE(7)
        PRE(8)  PRE(9)  PRE(10) PRE(11) PRE(12) PRE(13) PRE(14) PRE(15)
        #pragma unroll
        for (int w = 0; w < NW; ++w) {
            const unsigned pz = ((unsigned)__popc(tid & PLAN.ztid[w]) ^ (PLAN.zpm[w] >> d)) & 1u;
            const float hv = g_hw[w];
            const float sw = pz ? -hv : hv;
            ACW(0)  ACW(1)  ACW(2)  ACW(3)  ACW(4)  ACW(5)  ACW(6)  ACW(7)
            ACW(8)  ACW(9)  ACW(10) ACW(11) ACW(12) ACW(13) ACW(14) ACW(15)
        }
    } else {
        // RACE FIX: writes go to a NEW layout whose slots alias other
        // threads' unread sources. Everyone must finish reading first;
        // the state is safely parked in registers across this barrier.
        __syncthreads();
        // phys = t*16 ^ e ^ ((t&7)<<1): 8 bank-balanced ds_write_b128
        const unsigned wbase = (tid << 7) ^ ((tid & 7u) << 4);
        STP(0, a0,  a1)  STP(1, a2,  a3)  STP(2, a4,  a5)  STP(3, a6,  a7)
        STP(4, a8,  a9)  STP(5, a10, a11) STP(6, a12, a13) STP(7, a14, a15)
    }
}

__global__ __launch_bounds__(BLOCK) void qsim_kernel(
    const float* __restrict__ g_sr, const float* __restrict__ g_si,
    const float* __restrict__ g_params, const float* __restrict__ g_hw,
    const float* __restrict__ g_hb, float* __restrict__ g_out)
{
    extern __shared__ char lds[];                  // DIM * 8 B float2 slots
    __shared__ __align__(16) float gm[NGAT * 8];   // per gate: u00,u01,u10,u11 (complex)
    __shared__ float red[BLOCK / 64];

    const unsigned tid = threadIdx.x;
    const int b = blockIdx.x;
    const float* __restrict__ srcr = g_sr + (size_t)b * DIM;
    const float* __restrict__ srci = g_si + (size_t)b * DIM;

    // ---- gate matrices U = RZ @ RY @ RX, one gate per thread ----
    if (tid < NGAT) {
        const float tx = g_params[tid * 3 + 0];
        const float ty = g_params[tid * 3 + 1];
        const float tz = g_params[tid * 3 + 2];
        const float cx = cosf(0.5f * tx), sx = sinf(0.5f * tx);
        const float cy = cosf(0.5f * ty), sy = sinf(0.5f * ty);
        const float cz = cosf(0.5f * tz), sz = sinf(0.5f * tz);
        const float a00r = cy * cx,  a00i = sy * sx;
        const float a01r = -sy * cx, a01i = -cy * sx;
        const float a10r = sy * cx,  a10i = -cy * sx;
        const float a11r = cy * cx,  a11i = -sy * sx;
        gm[tid * 8 + 0] = cz * a00r + sz * a00i;
        gm[tid * 8 + 1] = cz * a00i - sz * a00r;
        gm[tid * 8 + 2] = cz * a01r + sz * a01i;
        gm[tid * 8 + 3] = cz * a01i - sz * a01r;
        gm[tid * 8 + 4] = cz * a10r - sz * a10i;
        gm[tid * 8 + 5] = cz * a10i + sz * a10r;
        gm[tid * 8 + 6] = cz * a11r - sz * a11i;
        gm[tid * 8 + 7] = cz * a11i + sz * a11r;
    }

    // ---- staging: coalesced float4 global reads; element x -> LDS slot x ----
    #pragma unroll
    for (int it = 0; it < 4; ++it) {
        const int x = (int)tid * 4 + it * 4096;
        const float4 re = *(const float4*)(srcr + x);
        const float4 im = *(const float4*)(srci + x);
        ((float2*)lds)[x + 0] = make_float2(re.x, im.x);
        ((float2*)lds)[x + 1] = make_float2(re.y, im.y);
        ((float2*)lds)[x + 2] = make_float2(re.z, im.z);
        ((float2*)lds)[x + 3] = make_float2(re.w, im.w);
    }

    float acc = 0.0f;
    do_batch<0>(lds, gm, tid, g_hw, acc);
    do_batch<1>(lds, gm, tid, g_hw, acc);
    do_batch<2>(lds, gm, tid, g_hw, acc);
    do_batch<3>(lds, gm, tid, g_hw, acc);
    do_batch<4>(lds, gm, tid, g_hw, acc);
    do_batch<5>(lds, gm, tid, g_hw, acc);
    do_batch<6>(lds, gm, tid, g_hw, acc);
    do_batch<7>(lds, gm, tid, g_hw, acc);
    do_batch<8>(lds, gm, tid, g_hw, acc);
    do_batch<9>(lds, gm, tid, g_hw, acc);
    do_batch<10>(lds, gm, tid, g_hw, acc);
    do_batch<11>(lds, gm, tid, g_hw, acc);

    // ---- reduce: wave shuffle then cross-wave via LDS ----
    #pragma unroll
    for (int off = 32; off > 0; off >>= 1) acc += __shfl_down(acc, off);
    const int lane = tid & 63, wid = tid >> 6;
    if (lane == 0) red[wid] = acc;
    __syncthreads();
    if (tid == 0) {
        float s = 0.0f;
        #pragma unroll
        for (int k = 0; k < BLOCK / 64; ++k) s += red[k];
        g_out[b] = s + g_hb[0];
    }
}

extern "C" void kernel_launch(void* const* d_in, const int* in_sizes, int n_in,
                              void* d_out, int out_size, void* d_ws, size_t ws_size,
                              hipStream_t stream) {
    const float* sr = (const float*)d_in[0];
    const float* si = (const float*)d_in[1];
    const float* vp = (const float*)d_in[2];
    const float* hw = (const float*)d_in[3];
    const float* hb = (const float*)d_in[4];
    float* out = (float*)d_out;

    dim3 grid(out_size);          // 1024 batch elements, one block each
    dim3 block(BLOCK);
    size_t shmem = (size_t)DIM * sizeof(float2);  // 128 KiB dynamic LDS
    qsim_kernel<<<grid, block, shmem, stream>>>(sr, si, vp, hw, hb, out);
}

// Round 9
// 263.727 us; speedup vs baseline: 2.0374x; 1.0827x over previous
//
#include <hip/hip_runtime.h>

#define NW 14
#define NL 3
#define NGAT 42            // 3 layers x 14 rotation gates
#define DIM 16384          // 2^14 amplitudes
#define BLOCK 1024

// ---------------------------------------------------------------------------
// MFMA formulation. CNOTs folded into GF(2) masks as before. Per batch the
// duality correction makes every coset see the SAME 16x16 gate matrix
// W = U3(x)U2(x)U1(x)U0, so each batch is one complex GEMM
//   D[16 x 1024] = W[16x16] x S[16 x 1024]
// done in bf16 hi/lo splits on the matrix cores:
//   Cr = [Wr|-Wi] x [Sr;Si],  Ci = [Wi|Wr] x [Sr;Si]   (K-pack k = 2*ein+c)
//   3 mfma each (hi*hi + lo*hi + hi*lo), fp32 accumulate.
// State stays fp32 complex in LDS (float2 entries); hi/lo split happens at
// read time so storage carries full precision.
//
// Inter-batch layout Psi (serving reader batch r): entry index of element
// x = rep_r(y) ^ combo_r[e'] is  idx = (y<<4) ^ ((y&7)<<1) ^ e'
// (the (y&7)<<1 term is a bank-spreading swizzle, GF(2)-linear). As a matrix:
// Psi = T o F_r^{-1} with T the target map — all constexpr via Lin algebra.
// Reads: 2x ds_read_b128 per tile (4 complex, natural e' order regardless of
// swizzle since XOR-addressing is used for the second b128). Writes by the
// producer batch are 4x ds_write_b64 per tile at Psi-mapped addresses.
// Race discipline: phase A (all reads) -> barrier -> phase B (mfma + writes),
// 2 barriers/batch, same as round 8.
//
// MFMA fragment maps used (gfx950 16x16x32 bf16):
//   A: row m = lane&15, k = (lane>>4)*8 + j   [m120-verified]
//   B: col n = lane&15, k = (lane>>4)*8 + j   [assumed symmetric to A]
//   D: col n = lane&15, row = (lane>>4)*4 + reg  [m89-verified]
// Batch 11 (ngates=2) runs fp32 butterflies in registers + epilogue
// (4-point Walsh + parity-mask signs) — no W table, best precision there.
// ---------------------------------------------------------------------------

typedef float        f4  __attribute__((ext_vector_type(4)));
typedef short        s8v __attribute__((ext_vector_type(8)));
typedef unsigned int u4v __attribute__((ext_vector_type(4)));

constexpr int parity14(int v) { int p = 0; for (int i = 0; i < NW; ++i) p ^= (v >> i) & 1; return p; }
constexpr int hibit(int v) { int h = -1; for (int i = 0; i < NW; ++i) if ((v >> i) & 1) h = i; return h; }

struct Lin { int col[NW]; };

constexpr int lin_apply(const Lin& M, int x) {
    int r = 0;
    for (int i = 0; i < NW; ++i) if ((x >> i) & 1) r ^= M.col[i];
    return r;
}
constexpr Lin lin_inverse(const Lin& M) {
    int E[NW] = {}, P[NW] = {};
    for (int i = 0; i < NW; ++i) {
        int v = M.col[i], p = 1 << i;
        while (v) {
            int h = hibit(v);
            if (!E[h]) { E[h] = v; P[h] = p; break; }
            v ^= E[h]; p ^= P[h];
        }
    }
    Lin R{};
    for (int i = 0; i < NW; ++i) {
        int v = 1 << i, p = 0;
        while (v) { int h = hibit(v); v ^= E[h]; p ^= P[h]; }
        R.col[i] = p;
    }
    return R;
}
constexpr Lin lin_compose(const Lin& A, const Lin& B) {
    Lin R{};
    for (int i = 0; i < NW; ++i) R.col[i] = lin_apply(A, B.col[i]);
    return R;
}

struct BatchP {
    int ngates;
    int gidx[4];
    unsigned wcB[16];   // byte: 8 * Psi_bi(combo_bi[e])   (write side, bi<11)
    unsigned wyB[10];   // byte: 8 * Psi_bi(cvec_bi[k])
};
struct PlanP {
    BatchP b[12];
    unsigned stB[14];   // staging: byte 8 * Psi_stage(1<<bit)
    unsigned ykey[14];  // tail: parity mask over key = y | (q<<10)
    int zsel[14];       // tail: Walsh index from basis[0,1] parities
};

constexpr PlanP make_planp() {
    PlanP P{};
    int R[NW] = {}, C[NW] = {};
    for (int p = 0; p < NW; ++p) { R[p] = 1 << p; C[p] = 1 << p; }

    int basisA[12][4] = {}; int comboA[12][16] = {}; int cvecA[12][10] = {};
    Lin F[12] = {};
    int bi = 0;
    for (int l = 0; l < NL; ++l) {
        const int sizes[4] = {4, 4, 4, 2};
        int w0 = 0;
        for (int s = 0; s < 4; ++s) {
            const int ng = sizes[s];
            P.b[bi].ngates = ng;
            int basis[4] = {}, rr[4] = {};
            for (int j = 0; j < ng; ++j) {
                int w = w0 + j, p = 13 - w;
                basis[j] = C[p];
                rr[j] = R[p];
                P.b[bi].gidx[j] = l * NW + w;
            }
            // echelon for independence
            int ech[4] = {}; int ne = 0;
            for (int j = 0; j < ng; ++j) {
                int v = basis[j];
                bool ch = true;
                while (ch) { ch = false;
                    for (int k = 0; k < ne; ++k)
                        if (v && ((v >> hibit(ech[k])) & 1)) { v ^= ech[k]; ch = true; }
                }
                ech[ne++] = v;
            }
            // pad to 4 from null space of gate parity masks
            int nb = ng;
            for (int cand = 1; cand < DIM && nb < 4; ++cand) {
                bool ok = true;
                for (int j = 0; j < ng; ++j) if (parity14(cand & rr[j])) { ok = false; break; }
                if (!ok) continue;
                int v = cand;
                bool ch = true;
                while (ch) { ch = false;
                    for (int k = 0; k < ne; ++k)
                        if (v && ((v >> hibit(ech[k])) & 1)) { v ^= ech[k]; ch = true; }
                }
                if (v) { basis[nb++] = cand; ech[ne++] = v; }
            }
            // pivots & non-pivot positions
            int piv[4] = {};
            for (int k = 0; k < 4; ++k) piv[k] = hibit(ech[k]);
            for (int a = 0; a < 4; ++a)
                for (int b2 = a + 1; b2 < 4; ++b2)
                    if (piv[b2] < piv[a]) { int t = piv[a]; piv[a] = piv[b2]; piv[b2] = t; }
            int npp[10] = {}; int nn = 0;
            for (int bit = 0; bit < NW; ++bit) {
                bool isp = false;
                for (int k = 0; k < 4; ++k) if (piv[k] == bit) isp = true;
                if (!isp) npp[nn++] = bit;
            }
            // duality-corrected coset directions
            for (int k = 0; k < 10; ++k) {
                int c = 1 << npp[k];
                for (int j = 0; j < ng; ++j) if ((rr[j] >> npp[k]) & 1) c ^= basis[j];
                cvecA[bi][k] = c;
            }
            for (int e = 0; e < 16; ++e) {
                int v = 0;
                for (int j = 0; j < 4; ++j) if ((e >> j) & 1) v ^= basis[j];
                comboA[bi][e] = v;
            }
            for (int j = 0; j < 4; ++j) basisA[bi][j] = basis[j];
            for (int j = 0; j < 4; ++j) F[bi].col[j] = basis[j];
            for (int k = 0; k < 10; ++k) F[bi].col[4 + k] = cvecA[bi][k];
            w0 += ng;
            ++bi;
        }
        // CNOT chain (w,w+1) w=0..12 then (13,0)
        for (int w = 0; w < NW; ++w) {
            int c = w, t = (w + 1) % NW;
            int pc = 13 - c, pt = 13 - t;
            R[pt] ^= R[pc];
            C[pc] ^= C[pt];
        }
    }
    // target map T: packed(e', y) -> idx = e' ^ (y<<4) ^ ((y&7)<<1)
    Lin T{};
    for (int j = 0; j < 4; ++j) T.col[j] = 1 << j;
    for (int k = 0; k < 10; ++k) T.col[4 + k] = (1 << (4 + k)) ^ (k < 3 ? (1 << (k + 1)) : 0);

    for (int i = 0; i < 11; ++i) {
        Lin Psi = lin_compose(T, lin_inverse(F[i + 1]));
        for (int e = 0; e < 16; ++e) P.b[i].wcB[e] = (unsigned)lin_apply(Psi, comboA[i][e]) * 8u;
        for (int k = 0; k < 10; ++k) P.b[i].wyB[k] = (unsigned)lin_apply(Psi, cvecA[i][k]) * 8u;
    }
    {
        Lin Psi0 = lin_compose(T, lin_inverse(F[0]));
        for (int bit = 0; bit < NW; ++bit) P.stB[bit] = (unsigned)lin_apply(Psi0, 1 << bit) * 8u;
    }
    for (int w = 0; w < NW; ++w) {
        int zrw = R[13 - w];
        unsigned ym = 0;
        for (int k = 0; k < 10; ++k) ym |= (unsigned)parity14(cvecA[11][k] & zrw) << k;
        int qm = parity14(basisA[11][2] & zrw) | (parity14(basisA[11][3] & zrw) << 1);
        P.ykey[w] = ym | ((unsigned)qm << 10);
        P.zsel[w] = parity14(basisA[11][0] & zrw) | (parity14(basisA[11][1] & zrw) << 1);
    }
    return P;
}

constexpr PlanP PL = make_planp();

// split fp32 (r,i) -> packed bf16 hi-dword (bf16(r)|bf16(i)<<16) and lo-dword
__device__ __forceinline__ void splitpk(float r, float i, unsigned& hi, unsigned& lo) {
    unsigned tr = __float_as_uint(r) + 0x8000u;
    unsigned ti = __float_as_uint(i) + 0x8000u;
    hi = __builtin_amdgcn_perm(ti, tr, 0x07060302u);
    float lr = r - __uint_as_float(tr & 0xffff0000u);
    float li = i - __uint_as_float(ti & 0xffff0000u);
    unsigned ur = __float_as_uint(lr) + 0x8000u;
    unsigned ui = __float_as_uint(li) + 0x8000u;
    lo = __builtin_amdgcn_perm(ui, ur, 0x07060302u);
}

__device__ __forceinline__ f4 mf(u4v a, u4v b, f4 c) {
    return __builtin_amdgcn_mfma_f32_16x16x32_bf16(
        __builtin_bit_cast(s8v, a), __builtin_bit_cast(s8v, b), c, 0, 0, 0);
}

template <int BI>
__device__ __forceinline__ void mfma_batch(char* __restrict__ lds, const float* __restrict__ gm,
                                           unsigned* __restrict__ atab) {
    constexpr BatchP B = PL.b[BI];
    const unsigned tid = threadIdx.x;
    const unsigned lane = tid & 63u, wid = tid >> 6;
    const unsigned n = lane & 15u, q = lane >> 4;

    __syncthreads();   // prev batch stores visible; prev atab reads done

    // ---- A-table build (threads 0..255), concurrent with phase A ----
    if (tid < 256) {
        const unsigned m = tid >> 4, ein = tid & 15u;
        float wr = 1.f, wi = 0.f;
        #pragma unroll
        for (int j = 0; j < 4; ++j) {
            if (j < B.ngates) {
                const unsigned mj = (m >> j) & 1u, ej = (ein >> j) & 1u;
                const float ur = gm[B.gidx[j] * 8 + (int)(mj * 4u + ej * 2u)];
                const float ui = gm[B.gidx[j] * 8 + (int)(mj * 4u + ej * 2u) + 1];
                const float nr = wr * ur - wi * ui;
                const float ni = wr * ui + wi * ur;
                wr = nr; wi = ni;
            }
        }
        if (B.ngates < 4 && (((m ^ ein) >> B.ngates) != 0u)) { wr = 0.f; wi = 0.f; }
        unsigned twr = __float_as_uint(wr) + 0x8000u;
        unsigned twi = __float_as_uint(wi) + 0x8000u;
        float lr = wr - __uint_as_float(twr & 0xffff0000u);
        float li = wi - __uint_as_float(twi & 0xffff0000u);
        unsigned tlr = __float_as_uint(lr) + 0x8000u;
        unsigned tli = __float_as_uint(li) + 0x8000u;
        const unsigned o = m * 16u + ein;
        atab[o]        = __builtin_amdgcn_perm(twi ^ 0x80000000u, twr, 0x07060302u); // (Wr_hi,-Wi_hi)
        atab[256 + o]  = __builtin_amdgcn_perm(tli ^ 0x80000000u, tlr, 0x07060302u); // (Wr_lo,-Wi_lo)
        atab[512 + o]  = __builtin_amdgcn_perm(twr, twi, 0x07060302u);               // (Wi_hi, Wr_hi)
        atab[768 + o]  = __builtin_amdgcn_perm(tlr, tli, 0x07060302u);               // (Wi_lo, Wr_lo)
    }

    // ---- phase A: read + convert all 4 tiles (reads must precede ALL writes) ----
    const unsigned bnq = ((wid << 10) ^ (n << 4) ^ ((n & 7u) << 1) ^ (q << 2)) << 3;
    u4v bhi[4], blo[4];
    #pragma unroll
    for (int t = 0; t < 4; ++t) {
        const unsigned a0 = bnq ^ ((unsigned)t << 11);
        const f4 v01 = *(const f4*)(lds + a0);
        const f4 v23 = *(const f4*)(lds + (a0 ^ 16u));
        unsigned h0, l0, h1, l1, h2, l2, h3, l3;
        splitpk(v01.x, v01.y, h0, l0);
        splitpk(v01.z, v01.w, h1, l1);
        splitpk(v23.x, v23.y, h2, l2);
        splitpk(v23.z, v23.w, h3, l3);
        u4v h; h.x = h0; h.y = h1; h.z = h2; h.w = h3;
        u4v l; l.x = l0; l.y = l1; l.z = l2; l.w = l3;
        bhi[t] = h; blo[t] = l;
    }

    __syncthreads();   // all reads done + atab ready

    // ---- phase B: mfma + write (new layout Psi_BI) ----
    const u4v A0 = *(const u4v*)&atab[(n << 4) + (q << 2)];
    const u4v A1 = *(const u4v*)&atab[256 + (n << 4) + (q << 2)];
    const u4v A2 = *(const u4v*)&atab[512 + (n << 4) + (q << 2)];
    const u4v A3 = *(const u4v*)&atab[768 + (n << 4) + (q << 2)];

    unsigned wb = 0;
    wb ^= (n & 1u) ? B.wyB[0] : 0u;
    wb ^= (n & 2u) ? B.wyB[1] : 0u;
    wb ^= (n & 4u) ? B.wyB[2] : 0u;
    wb ^= (n & 8u) ? B.wyB[3] : 0u;
    wb ^= (wid & 1u) ? B.wyB[6] : 0u;
    wb ^= (wid & 2u) ? B.wyB[7] : 0u;
    wb ^= (wid & 4u) ? B.wyB[8] : 0u;
    wb ^= (wid & 8u) ? B.wyB[9] : 0u;
    wb ^= (q & 1u) ? B.wcB[4] : 0u;
    wb ^= (q & 2u) ? B.wcB[8] : 0u;

    #pragma unroll
    for (int t = 0; t < 4; ++t) {
        f4 ar = {0.f, 0.f, 0.f, 0.f};
        f4 ai = {0.f, 0.f, 0.f, 0.f};
        ar = mf(A0, bhi[t], ar);
        ai = mf(A2, bhi[t], ai);
        ar = mf(A1, bhi[t], ar);
        ai = mf(A3, bhi[t], ai);
        ar = mf(A0, blo[t], ar);
        ai = mf(A2, blo[t], ai);
        const unsigned wt = wb ^ ((t & 1) ? B.wyB[4] : 0u) ^ ((t & 2) ? B.wyB[5] : 0u);
        *(float2*)(lds + (wt ^ B.wcB[0])) = make_float2(ar.x, ai.x);
        *(float2*)(lds + (wt ^ B.wcB[1])) = make_float2(ar.y, ai.y);
        *(float2*)(lds + (wt ^ B.wcB[2])) = make_float2(ar.z, ai.z);
        *(float2*)(lds + (wt ^ B.wcB[3])) = make_float2(ar.w, ai.w);
    }
}

// complex 2x2 butterfly, ua = (u00r,u00i,u01r,u01i), ub = (u10r,u10i,u11r,u11i)
#define BFC(A, B_, ua, ub) { const float2 t0 = A, t1 = B_; \
    A.x  = ua.x * t0.x - ua.y * t0.y + ua.z * t1.x - ua.w * t1.y; \
    A.y  = ua.x * t0.y + ua.y * t0.x + ua.z * t1.y + ua.w * t1.x; \
    B_.x = ub.x * t0.x - ub.y * t0.y + ub.z * t1.x - ub.w * t1.y; \
    B_.y = ub.x * t0.y + ub.y * t0.x + ub.z * t1.y + ub.w * t1.x; }

__device__ __forceinline__ float tail_batch(char* __restrict__ lds, const float* __restrict__ gm,
                                            const float* __restrict__ g_hw) {
    constexpr BatchP B = PL.b[11];   // ngates == 2
    const unsigned tid = threadIdx.x;
    const unsigned lane = tid & 63u, wid = tid >> 6;
    const unsigned n = lane & 15u, q = lane >> 4;
    __syncthreads();
    const f4 u0a = *(const f4*)&gm[B.gidx[0] * 8];
    const f4 u0b = *(const f4*)&gm[B.gidx[0] * 8 + 4];
    const f4 u1a = *(const f4*)&gm[B.gidx[1] * 8];
    const f4 u1b = *(const f4*)&gm[B.gidx[1] * 8 + 4];
    float hwv[NW];
    #pragma unroll
    for (int w = 0; w < NW; ++w) hwv[w] = g_hw[w];
    float acc = 0.f;
    const unsigned bnq = ((wid << 10) ^ (n << 4) ^ ((n & 7u) << 1) ^ (q << 2)) << 3;
    #pragma unroll
    for (int t = 0; t < 4; ++t) {
        const unsigned a0 = bnq ^ ((unsigned)t << 11);
        const f4 v01 = *(const f4*)(lds + a0);
        const f4 v23 = *(const f4*)(lds + (a0 ^ 16u));
        float2 c0 = make_float2(v01.x, v01.y);
        float2 c1 = make_float2(v01.z, v01.w);
        float2 c2 = make_float2(v23.x, v23.y);
        float2 c3 = make_float2(v23.z, v23.w);
        BFC(c0, c1, u0a, u0b)  BFC(c2, c3, u0a, u0b)   // gate 0: slot bit 0
        BFC(c0, c2, u1a, u1b)  BFC(c1, c3, u1a, u1b)   // gate 1: slot bit 1
        const float p0 = c0.x * c0.x + c0.y * c0.y;
        const float p1 = c1.x * c1.x + c1.y * c1.y;
        const float p2 = c2.x * c2.x + c2.y * c2.y;
        const float p3 = c3.x * c3.x + c3.y * c3.y;
        const float sa = p0 + p1, sb = p0 - p1, sc = p2 + p3, sd = p2 - p3;
        const float W4[4] = {sa + sc, sb + sd, sa - sc, sb - sd};
        const unsigned y = (wid << 6) | ((unsigned)t << 4) | n;
        const unsigned key = y | (q << 10);
        #pragma unroll
        for (int w = 0; w < NW; ++w) {
            const unsigned sg = ((unsigned)__popc(key & PL.ykey[w])) << 31;
            const float s = __uint_as_float(__float_as_uint(hwv[w]) ^ sg);
            acc += W4[PL.zsel[w]] * s;
        }
    }
    return acc;
}

__global__ __launch_bounds__(BLOCK) void qsim_kernel(
    const float* __restrict__ g_sr, const float* __restrict__ g_si,
    const float* __restrict__ g_params, const float* __restrict__ g_hw,
    const float* __restrict__ g_hb, float* __restrict__ g_out)
{
    extern __shared__ char lds[];                    // 16384 float2 entries (128 KiB)
    __shared__ __align__(16) float gm[NGAT * 8];
    __shared__ __align__(16) unsigned atab[1024];    // 4 A-tables, 16x32 bf16 each
    __shared__ float red[BLOCK / 64];

    const unsigned tid = threadIdx.x;
    const int b = blockIdx.x;
    const float* __restrict__ srcr = g_sr + (size_t)b * DIM;
    const float* __restrict__ srci = g_si + (size_t)b * DIM;

    // ---- gate matrices U = RZ @ RY @ RX ----
    if (tid < NGAT) {
        const float tx = g_params[tid * 3 + 0];
        const float ty = g_params[tid * 3 + 1];
        const float tz = g_params[tid * 3 + 2];
        const float cx = cosf(0.5f * tx), sx = sinf(0.5f * tx);
        const float cy = cosf(0.5f * ty), sy = sinf(0.5f * ty);
        const float cz = cosf(0.5f * tz), sz = sinf(0.5f * tz);
        const float a00r = cy * cx,  a00i = sy * sx;
        const float a01r = -sy * cx, a01i = -cy * sx;
        const float a10r = sy * cx,  a10i = -cy * sx;
        const float a11r = cy * cx,  a11i = -sy * sx;
        gm[tid * 8 + 0] = cz * a00r + sz * a00i;
        gm[tid * 8 + 1] = cz * a00i - sz * a00r;
        gm[tid * 8 + 2] = cz * a01r + sz * a01i;
        gm[tid * 8 + 3] = cz * a01i - sz * a01r;
        gm[tid * 8 + 4] = cz * a10r - sz * a10i;
        gm[tid * 8 + 5] = cz * a10i + sz * a10r;
        gm[tid * 8 + 6] = cz * a11r - sz * a11i;
        gm[tid * 8 + 7] = cz * a11i + sz * a11r;
    }

    // ---- staging: global fp32 -> Psi_0 layout (float2 entries) ----
    unsigned bb = 0;
    #pragma unroll
    for (int k = 0; k < 10; ++k) bb ^= ((tid >> k) & 1u) ? PL.stB[k + 2] : 0u;
    #pragma unroll
    for (int it = 0; it < 4; ++it) {
        const int x = (int)tid * 4 + it * 4096;
        const f4 r4 = *(const f4*)(srcr + x);
        const f4 i4 = *(const f4*)(srci + x);
        const unsigned base = bb ^ ((it & 1) ? PL.stB[12] : 0u) ^ ((it & 2) ? PL.stB[13] : 0u);
        *(float2*)(lds + base) = make_float2(r4.x, i4.x);
        *(float2*)(lds + (base ^ PL.stB[0])) = make_float2(r4.y, i4.y);
        *(float2*)(lds + (base ^ PL.stB[1])) = make_float2(r4.z, i4.z);
        *(float2*)(lds + (base ^ (PL.stB[0] ^ PL.stB[1]))) = make_float2(r4.w, i4.w);
    }

    mfma_batch<0>(lds, gm, atab);
    mfma_batch<1>(lds, gm, atab);
    mfma_batch<2>(lds, gm, atab);
    mfma_batch<3>(lds, gm, atab);
    mfma_batch<4>(lds, gm, atab);
    mfma_batch<5>(lds, gm, atab);
    mfma_batch<6>(lds, gm, atab);
    mfma_batch<7>(lds, gm, atab);
    mfma_batch<8>(lds, gm, atab);
    mfma_batch<9>(lds, gm, atab);
    mfma_batch<10>(lds, gm, atab);

    float acc = tail_batch(lds, gm, g_hw);

    // ---- reduce ----
    #pragma unroll
    for (int off = 32; off > 0; off >>= 1) acc += __shfl_down(acc, off);
    const int lane = tid & 63, wid = tid >> 6;
    if (lane == 0) red[wid] = acc;
    __syncthreads();
    if (tid == 0) {
        float s = 0.0f;
        #pragma unroll
        for (int k = 0; k < BLOCK / 64; ++k) s += red[k];
        g_out[b] = s + g_hb[0];
    }
}

extern "C" void kernel_launch(void* const* d_in, const int* in_sizes, int n_in,
                              void* d_out, int out_size, void* d_ws, size_t ws_size,
                              hipStream_t stream) {
    const float* sr = (const float*)d_in[0];
    const float* si = (const float*)d_in[1];
    const float* vp = (const float*)d_in[2];
    const float* hw = (const float*)d_in[3];
    const float* hb = (const float*)d_in[4];
    float* out = (float*)d_out;

    dim3 grid(out_size);          // 1024 batch elements, one block each
    dim3 block(BLOCK);
    size_t shmem = (size_t)DIM * sizeof(float2);  // 128 KiB dynamic LDS
    qsim_kernel<<<grid, block, shmem, stream>>>(sr, si, vp, hw, hb, out);
}

// Round 11
// 246.612 us; speedup vs baseline: 2.1788x; 1.0694x over previous
//
#include <hip/hip_runtime.h>

#define NW 14
#define NL 3
#define NGAT 42            // 3 layers x 14 rotation gates
#define DIM 16384          // 2^14 amplitudes
#define BLOCK 1024

// ---------------------------------------------------------------------------
// MFMA formulation (round 9) with WRITER-FRAME layout (round 10/11).
// Per batch, duality correction makes every coset see the same 16x16 matrix
// W = U3(x)U2(x)U1(x)U0 -> batch = complex GEMM D[16x1024] = W x S, done as
// bf16 hi/lo splits on matrix cores (3 mfma per r/i output: hihi+lohi+hilo),
// fp32 state in LDS.
//
// Layout after batch w is Lambda_w = T o F_w^{-1} with
//   T(y,e) = (y<<4) ^ e ^ ((y&7)<<1)
// -> the WRITER's D-fragment stores are clean bank-balanced b128s (this
//    exact pattern measured benign as round 9's reads);
// -> the READER gathers via Lambda_{r-1} o F_r constants: 4 scattered b64
//    per tile (round 8's measured-benign profile, 6e6 conflicts).
// Round 9 had the opposite orientation; its scattered b64 WRITES through
// arbitrary Psi constants caused SQ_LDS_BANK_CONFLICT 3.6e7 (~58us).
// Batch 0 reads clean T directly (staging writes into Lambda_0, unchanged).
// Round 11: fixed ext-vector store init (make_float4 -> brace init).
// ---------------------------------------------------------------------------

typedef float        f4  __attribute__((ext_vector_type(4)));
typedef short        s8v __attribute__((ext_vector_type(8)));
typedef unsigned int u4v __attribute__((ext_vector_type(4)));

constexpr int parity14(int v) { int p = 0; for (int i = 0; i < NW; ++i) p ^= (v >> i) & 1; return p; }
constexpr int hibit(int v) { int h = -1; for (int i = 0; i < NW; ++i) if ((v >> i) & 1) h = i; return h; }

struct Lin { int col[NW]; };

constexpr int lin_apply(const Lin& M, int x) {
    int r = 0;
    for (int i = 0; i < NW; ++i) if ((x >> i) & 1) r ^= M.col[i];
    return r;
}
constexpr Lin lin_inverse(const Lin& M) {
    int E[NW] = {}, P[NW] = {};
    for (int i = 0; i < NW; ++i) {
        int v = M.col[i], p = 1 << i;
        while (v) {
            int h = hibit(v);
            if (!E[h]) { E[h] = v; P[h] = p; break; }
            v ^= E[h]; p ^= P[h];
        }
    }
    Lin R{};
    for (int i = 0; i < NW; ++i) {
        int v = 1 << i, p = 0;
        while (v) { int h = hibit(v); v ^= E[h]; p ^= P[h]; }
        R.col[i] = p;
    }
    return R;
}
constexpr Lin lin_compose(const Lin& A, const Lin& B) {
    Lin R{};
    for (int i = 0; i < NW; ++i) R.col[i] = lin_apply(A, B.col[i]);
    return R;
}

struct BatchP {
    int ngates;
    int gidx[4];
    unsigned rdy[10];   // byte: 8 * Lambda_{r-1}(cvec_r[k])  (y-bit directions)
    unsigned rde[16];   // byte: 8 * Lambda_{r-1}(combo_r[e]) (e-directions)
};
struct PlanP {
    BatchP b[12];
    unsigned stB[14];   // staging: byte 8 * Lambda_0(1<<bit)
    unsigned ykey[14];  // tail: parity mask over key = y | (q<<10)
    int zsel[14];       // tail: Walsh index from basis[0,1] parities
};

constexpr PlanP make_planp() {
    PlanP P{};
    int R[NW] = {}, C[NW] = {};
    for (int p = 0; p < NW; ++p) { R[p] = 1 << p; C[p] = 1 << p; }

    int basisA[12][4] = {}; int comboA[12][16] = {}; int cvecA[12][10] = {};
    Lin F[12] = {};
    int bi = 0;
    for (int l = 0; l < NL; ++l) {
        const int sizes[4] = {4, 4, 4, 2};
        int w0 = 0;
        for (int s = 0; s < 4; ++s) {
            const int ng = sizes[s];
            P.b[bi].ngates = ng;
            int basis[4] = {}, rr[4] = {};
            for (int j = 0; j < ng; ++j) {
                int w = w0 + j, p = 13 - w;
                basis[j] = C[p];
                rr[j] = R[p];
                P.b[bi].gidx[j] = l * NW + w;
            }
            // echelon for independence
            int ech[4] = {}; int ne = 0;
            for (int j = 0; j < ng; ++j) {
                int v = basis[j];
                bool ch = true;
                while (ch) { ch = false;
                    for (int k = 0; k < ne; ++k)
                        if (v && ((v >> hibit(ech[k])) & 1)) { v ^= ech[k]; ch = true; }
                }
                ech[ne++] = v;
            }
            // pad to 4 from null space of gate parity masks
            int nb = ng;
            for (int cand = 1; cand < DIM && nb < 4; ++cand) {
                bool ok = true;
                for (int j = 0; j < ng; ++j) if (parity14(cand & rr[j])) { ok = false; break; }
                if (!ok) continue;
                int v = cand;
                bool ch = true;
                while (ch) { ch = false;
                    for (int k = 0; k < ne; ++k)
                        if (v && ((v >> hibit(ech[k])) & 1)) { v ^= ech[k]; ch = true; }
                }
                if (v) { basis[nb++] = cand; ech[ne++] = v; }
            }
            // pivots & non-pivot positions
            int piv[4] = {};
            for (int k = 0; k < 4; ++k) piv[k] = hibit(ech[k]);
            for (int a = 0; a < 4; ++a)
                for (int b2 = a + 1; b2 < 4; ++b2)
                    if (piv[b2] < piv[a]) { int t = piv[a]; piv[a] = piv[b2]; piv[b2] = t; }
            int npp[10] = {}; int nn = 0;
            for (int bit = 0; bit < NW; ++bit) {
                bool isp = false;
                for (int k = 0; k < 4; ++k) if (piv[k] == bit) isp = true;
                if (!isp) npp[nn++] = bit;
            }
            // duality-corrected coset directions
            for (int k = 0; k < 10; ++k) {
                int c = 1 << npp[k];
                for (int j = 0; j < ng; ++j) if ((rr[j] >> npp[k]) & 1) c ^= basis[j];
                cvecA[bi][k] = c;
            }
            for (int e = 0; e < 16; ++e) {
                int v = 0;
                for (int j = 0; j < 4; ++j) if ((e >> j) & 1) v ^= basis[j];
                comboA[bi][e] = v;
            }
            for (int j = 0; j < 4; ++j) basisA[bi][j] = basis[j];
            for (int j = 0; j < 4; ++j) F[bi].col[j] = basis[j];
            for (int k = 0; k < 10; ++k) F[bi].col[4 + k] = cvecA[bi][k];
            w0 += ng;
            ++bi;
        }
        // CNOT chain (w,w+1) w=0..12 then (13,0)
        for (int w = 0; w < NW; ++w) {
            int c = w, t = (w + 1) % NW;
            int pc = 13 - c, pt = 13 - t;
            R[pt] ^= R[pc];
            C[pc] ^= C[pt];
        }
    }
    // T: packed(e, y) -> idx = e ^ (y<<4) ^ ((y&7)<<1)
    Lin T{};
    for (int j = 0; j < 4; ++j) T.col[j] = 1 << j;
    for (int k = 0; k < 10; ++k) T.col[4 + k] = (1 << (4 + k)) ^ (k < 3 ? (1 << (k + 1)) : 0);

    // Lambda_w = T o F_w^{-1}; staging uses Lambda_0, reader r uses Lambda_{r-1}
    {
        Lin L0 = lin_compose(T, lin_inverse(F[0]));
        for (int bit = 0; bit < NW; ++bit) P.stB[bit] = (unsigned)lin_apply(L0, 1 << bit) * 8u;
    }
    for (int r = 1; r < 12; ++r) {
        Lin Lw = lin_compose(T, lin_inverse(F[r - 1]));
        for (int k = 0; k < 10; ++k) P.b[r].rdy[k] = (unsigned)lin_apply(Lw, cvecA[r][k]) * 8u;
        for (int e = 0; e < 16; ++e) P.b[r].rde[e] = (unsigned)lin_apply(Lw, comboA[r][e]) * 8u;
    }
    for (int w = 0; w < NW; ++w) {
        int zrw = R[13 - w];
        unsigned ym = 0;
        for (int k = 0; k < 10; ++k) ym |= (unsigned)parity14(cvecA[11][k] & zrw) << k;
        int qm = parity14(basisA[11][2] & zrw) | (parity14(basisA[11][3] & zrw) << 1);
        P.ykey[w] = ym | ((unsigned)qm << 10);
        P.zsel[w] = parity14(basisA[11][0] & zrw) | (parity14(basisA[11][1] & zrw) << 1);
    }
    return P;
}

constexpr PlanP PL = make_planp();

// fp32 (r,i) -> packed bf16 hi dword + lo dword. hi = truncation (lo absorbs
// the residual; round only lo) — 8 VALU.
__device__ __forceinline__ void splitpk(float r, float i, unsigned& hi, unsigned& lo) {
    const unsigned tr = __float_as_uint(r);
    const unsigned ti = __float_as_uint(i);
    hi = __builtin_amdgcn_perm(ti, tr, 0x07060302u);
    const float lr = r - __uint_as_float(tr & 0xffff0000u);
    const float li = i - __uint_as_float(ti & 0xffff0000u);
    const unsigned ur = __float_as_uint(lr) + 0x8000u;
    const unsigned ui = __float_as_uint(li) + 0x8000u;
    lo = __builtin_amdgcn_perm(ui, ur, 0x07060302u);
}

__device__ __forceinline__ f4 mf(u4v a, u4v b, f4 c) {
    return __builtin_amdgcn_mfma_f32_16x16x32_bf16(
        __builtin_bit_cast(s8v, a), __builtin_bit_cast(s8v, b), c, 0, 0, 0);
}

// scattered-read base for reader batch B: XOR-select over y-bits (n,wid) and
// q-part; per-tile t adds rdy[4]/rdy[5]; 4 entries at {0, rde1, rde2, rde3}.
#define RD_SREP(B)                                                     \
    unsigned srep = 0;                                                 \
    srep ^= (n & 1u)   ? B.rdy[0] : 0u;                                \
    srep ^= (n & 2u)   ? B.rdy[1] : 0u;                                \
    srep ^= (n & 4u)   ? B.rdy[2] : 0u;                                \
    srep ^= (n & 8u)   ? B.rdy[3] : 0u;                                \
    srep ^= (wid & 1u) ? B.rdy[6] : 0u;                                \
    srep ^= (wid & 2u) ? B.rdy[7] : 0u;                                \
    srep ^= (wid & 4u) ? B.rdy[8] : 0u;                                \
    srep ^= (wid & 8u) ? B.rdy[9] : 0u;                                \
    srep ^= (q & 1u)   ? B.rde[4] : 0u;                                \
    srep ^= (q & 2u)   ? B.rde[8] : 0u;

template <int BI>
__device__ __forceinline__ void mfma_batch(char* __restrict__ lds, const float* __restrict__ gm,
                                           unsigned* __restrict__ atab) {
    constexpr BatchP B = PL.b[BI];
    const unsigned tid = threadIdx.x;
    const unsigned lane = tid & 63u, wid = tid >> 6;
    const unsigned n = lane & 15u, q = lane >> 4;

    __syncthreads();   // prev batch stores visible; prev atab reads done

    // ---- A-table build (threads 0..255), concurrent with phase A ----
    if (tid < 256) {
        const unsigned m = tid >> 4, ein = tid & 15u;
        float wr = 1.f, wi = 0.f;
        #pragma unroll
        for (int j = 0; j < 4; ++j) {
            if (j < B.ngates) {
                const unsigned mj = (m >> j) & 1u, ej = (ein >> j) & 1u;
                const float ur = gm[B.gidx[j] * 8 + (int)(mj * 4u + ej * 2u)];
                const float ui = gm[B.gidx[j] * 8 + (int)(mj * 4u + ej * 2u) + 1];
                const float nr = wr * ur - wi * ui;
                const float ni = wr * ui + wi * ur;
                wr = nr; wi = ni;
            }
        }
        if (B.ngates < 4 && (((m ^ ein) >> B.ngates) != 0u)) { wr = 0.f; wi = 0.f; }
        unsigned twr = __float_as_uint(wr) + 0x8000u;
        unsigned twi = __float_as_uint(wi) + 0x8000u;
        float lr = wr - __uint_as_float(twr & 0xffff0000u);
        float li = wi - __uint_as_float(twi & 0xffff0000u);
        unsigned tlr = __float_as_uint(lr) + 0x8000u;
        unsigned tli = __float_as_uint(li) + 0x8000u;
        const unsigned o = m * 16u + ein;
        atab[o]        = __builtin_amdgcn_perm(twi ^ 0x80000000u, twr, 0x07060302u); // (Wr_hi,-Wi_hi)
        atab[256 + o]  = __builtin_amdgcn_perm(tli ^ 0x80000000u, tlr, 0x07060302u); // (Wr_lo,-Wi_lo)
        atab[512 + o]  = __builtin_amdgcn_perm(twr, twi, 0x07060302u);               // (Wi_hi, Wr_hi)
        atab[768 + o]  = __builtin_amdgcn_perm(tlr, tli, 0x07060302u);               // (Wi_lo, Wr_lo)
    }

    // clean T-frame base (used by batch-0 reads and by ALL writes)
    const unsigned bnq = ((wid << 10) ^ (n << 4) ^ ((n & 7u) << 1) ^ (q << 2)) << 3;

    // ---- phase A: read + convert all 4 tiles (all reads precede all writes) ----
    u4v bhi[4], blo[4];
    if constexpr (BI == 0) {
        #pragma unroll
        for (int t = 0; t < 4; ++t) {
            const unsigned a0 = bnq ^ ((unsigned)t << 11);
            const f4 v01 = *(const f4*)(lds + a0);
            const f4 v23 = *(const f4*)(lds + (a0 ^ 16u));
            unsigned h0, l0, h1, l1, h2, l2, h3, l3;
            splitpk(v01.x, v01.y, h0, l0);
            splitpk(v01.z, v01.w, h1, l1);
            splitpk(v23.x, v23.y, h2, l2);
            splitpk(v23.z, v23.w, h3, l3);
            u4v h; h.x = h0; h.y = h1; h.z = h2; h.w = h3;
            u4v l; l.x = l0; l.y = l1; l.z = l2; l.w = l3;
            bhi[t] = h; blo[t] = l;
        }
    } else {
        RD_SREP(B)
        #pragma unroll
        for (int t = 0; t < 4; ++t) {
            const unsigned st = srep ^ ((t & 1) ? B.rdy[4] : 0u) ^ ((t & 2) ? B.rdy[5] : 0u);
            const float2 c0 = *(const float2*)(lds + st);
            const float2 c1 = *(const float2*)(lds + (st ^ B.rde[1]));
            const float2 c2 = *(const float2*)(lds + (st ^ B.rde[2]));
            const float2 c3 = *(const float2*)(lds + (st ^ B.rde[3]));
            unsigned h0, l0, h1, l1, h2, l2, h3, l3;
            splitpk(c0.x, c0.y, h0, l0);
            splitpk(c1.x, c1.y, h1, l1);
            splitpk(c2.x, c2.y, h2, l2);
            splitpk(c3.x, c3.y, h3, l3);
            u4v h; h.x = h0; h.y = h1; h.z = h2; h.w = h3;
            u4v l; l.x = l0; l.y = l1; l.z = l2; l.w = l3;
            bhi[t] = h; blo[t] = l;
        }
    }

    __syncthreads();   // all reads done + atab ready

    // ---- phase B: mfma + clean writer-frame b128 stores ----
    const u4v A0 = *(const u4v*)&atab[(n << 4) + (q << 2)];
    const u4v A1 = *(const u4v*)&atab[256 + (n << 4) + (q << 2)];
    const u4v A2 = *(const u4v*)&atab[512 + (n << 4) + (q << 2)];
    const u4v A3 = *(const u4v*)&atab[768 + (n << 4) + (q << 2)];

    #pragma unroll
    for (int t = 0; t < 4; ++t) {
        f4 ar = {0.f, 0.f, 0.f, 0.f};
        f4 ai = {0.f, 0.f, 0.f, 0.f};
        ar = mf(A0, bhi[t], ar);
        ai = mf(A2, bhi[t], ai);
        ar = mf(A1, bhi[t], ar);
        ai = mf(A3, bhi[t], ai);
        ar = mf(A0, blo[t], ar);
        ai = mf(A2, blo[t], ai);
        const unsigned a0 = bnq ^ ((unsigned)t << 11);
        const f4 s01 = {ar.x, ai.x, ar.y, ai.y};
        const f4 s23 = {ar.z, ai.z, ar.w, ai.w};
        *(f4*)(lds + a0)         = s01;
        *(f4*)(lds + (a0 ^ 16u)) = s23;
    }
}

// complex 2x2 butterfly
#define BFC(A, B_, ua, ub) { const float2 t0 = A, t1 = B_; \
    A.x  = ua.x * t0.x - ua.y * t0.y + ua.z * t1.x - ua.w * t1.y; \
    A.y  = ua.x * t0.y + ua.y * t0.x + ua.z * t1.y + ua.w * t1.x; \
    B_.x = ub.x * t0.x - ub.y * t0.y + ub.z * t1.x - ub.w * t1.y; \
    B_.y = ub.x * t0.y + ub.y * t0.x + ub.z * t1.y + ub.w * t1.x; }

__device__ __forceinline__ float tail_batch(char* __restrict__ lds, const float* __restrict__ gm,
                                            const float* __restrict__ g_hw) {
    constexpr BatchP B = PL.b[11];   // ngates == 2
    const unsigned tid = threadIdx.x;
    const unsigned lane = tid & 63u, wid = tid >> 6;
    const unsigned n = lane & 15u, q = lane >> 4;
    __syncthreads();
    const f4 u0a = *(const f4*)&gm[B.gidx[0] * 8];
    const f4 u0b = *(const f4*)&gm[B.gidx[0] * 8 + 4];
    const f4 u1a = *(const f4*)&gm[B.gidx[1] * 8];
    const f4 u1b = *(const f4*)&gm[B.gidx[1] * 8 + 4];
    float hwv[NW];
    #pragma unroll
    for (int w = 0; w < NW; ++w) hwv[w] = g_hw[w];
    float acc = 0.f;
    RD_SREP(B)
    #pragma unroll
    for (int t = 0; t < 4; ++t) {
        const unsigned st = srep ^ ((t & 1) ? B.rdy[4] : 0u) ^ ((t & 2) ? B.rdy[5] : 0u);
        float2 c0 = *(const float2*)(lds + st);
        float2 c1 = *(const float2*)(lds + (st ^ B.rde[1]));
        float2 c2 = *(const float2*)(lds + (st ^ B.rde[2]));
        float2 c3 = *(const float2*)(lds + (st ^ B.rde[3]));
        BFC(c0, c1, u0a, u0b)  BFC(c2, c3, u0a, u0b)   // gate 0: slot bit 0
        BFC(c0, c2, u1a, u1b)  BFC(c1, c3, u1a, u1b)   // gate 1: slot bit 1
        const float p0 = c0.x * c0.x + c0.y * c0.y;
        const float p1 = c1.x * c1.x + c1.y * c1.y;
        const float p2 = c2.x * c2.x + c2.y * c2.y;
        const float p3 = c3.x * c3.x + c3.y * c3.y;
        const float sa = p0 + p1, sb = p0 - p1, sc = p2 + p3, sd = p2 - p3;
        const float W4[4] = {sa + sc, sb + sd, sa - sc, sb - sd};
        const unsigned y = (wid << 6) | ((unsigned)t << 4) | n;
        const unsigned key = y | (q << 10);
        #pragma unroll
        for (int w = 0; w < NW; ++w) {
            const unsigned sg = ((unsigned)__popc(key & PL.ykey[w])) << 31;
            const float s = __uint_as_float(__float_as_uint(hwv[w]) ^ sg);
            acc += W4[PL.zsel[w]] * s;
        }
    }
    return acc;
}

__global__ __launch_bounds__(BLOCK) void qsim_kernel(
    const float* __restrict__ g_sr, const float* __restrict__ g_si,
    const float* __restrict__ g_params, const float* __restrict__ g_hw,
    const float* __restrict__ g_hb, float* __restrict__ g_out)
{
    extern __shared__ char lds[];                    // 16384 float2 entries (128 KiB)
    __shared__ __align__(16) float gm[NGAT * 8];
    __shared__ __align__(16) unsigned atab[1024];    // 4 A-tables, 16x32 bf16 each
    __shared__ float red[BLOCK / 64];

    const unsigned tid = threadIdx.x;
    const int b = blockIdx.x;
    const float* __restrict__ srcr = g_sr + (size_t)b * DIM;
    const float* __restrict__ srci = g_si + (size_t)b * DIM;

    // ---- gate matrices U = RZ @ RY @ RX ----
    if (tid < NGAT) {
        const float tx = g_params[tid * 3 + 0];
        const float ty = g_params[tid * 3 + 1];
        const float tz = g_params[tid * 3 + 2];
        const float cx = cosf(0.5f * tx), sx = sinf(0.5f * tx);
        const float cy = cosf(0.5f * ty), sy = sinf(0.5f * ty);
        const float cz = cosf(0.5f * tz), sz = sinf(0.5f * tz);
        const float a00r = cy * cx,  a00i = sy * sx;
        const float a01r = -sy * cx, a01i = -cy * sx;
        const float a10r = sy * cx,  a10i = -cy * sx;
        const float a11r = cy * cx,  a11i = -sy * sx;
        gm[tid * 8 + 0] = cz * a00r + sz * a00i;
        gm[tid * 8 + 1] = cz * a00i - sz * a00r;
        gm[tid * 8 + 2] = cz * a01r + sz * a01i;
        gm[tid * 8 + 3] = cz * a01i - sz * a01r;
        gm[tid * 8 + 4] = cz * a10r - sz * a10i;
        gm[tid * 8 + 5] = cz * a10i + sz * a10r;
        gm[tid * 8 + 6] = cz * a11r - sz * a11i;
        gm[tid * 8 + 7] = cz * a11i + sz * a11r;
    }

    // ---- staging: global fp32 -> Lambda_0 layout (so batch 0 reads clean T) ----
    unsigned bb = 0;
    #pragma unroll
    for (int k = 0; k < 10; ++k) bb ^= ((tid >> k) & 1u) ? PL.stB[k + 2] : 0u;
    #pragma unroll
    for (int it = 0; it < 4; ++it) {
        const int x = (int)tid * 4 + it * 4096;
        const f4 r4 = *(const f4*)(srcr + x);
        const f4 i4 = *(const f4*)(srci + x);
        const unsigned base = bb ^ ((it & 1) ? PL.stB[12] : 0u) ^ ((it & 2) ? PL.stB[13] : 0u);
        *(float2*)(lds + base) = make_float2(r4.x, i4.x);
        *(float2*)(lds + (base ^ PL.stB[0])) = make_float2(r4.y, i4.y);
        *(float2*)(lds + (base ^ PL.stB[1])) = make_float2(r4.z, i4.z);
        *(float2*)(lds + (base ^ (PL.stB[0] ^ PL.stB[1]))) = make_float2(r4.w, i4.w);
    }

    mfma_batch<0>(lds, gm, atab);
    mfma_batch<1>(lds, gm, atab);
    mfma_batch<2>(lds, gm, atab);
    mfma_batch<3>(lds, gm, atab);
    mfma_batch<4>(lds, gm, atab);
    mfma_batch<5>(lds, gm, atab);
    mfma_batch<6>(lds, gm, atab);
    mfma_batch<7>(lds, gm, atab);
    mfma_batch<8>(lds, gm, atab);
    mfma_batch<9>(lds, gm, atab);
    mfma_batch<10>(lds, gm, atab);

    float acc = tail_batch(lds, gm, g_hw);

    // ---- reduce ----
    #pragma unroll
    for (int off = 32; off > 0; off >>= 1) acc += __shfl_down(acc, off);
    const int lane = tid & 63, wid = tid >> 6;
    if (lane == 0) red[wid] = acc;
    __syncthreads();
    if (tid == 0) {
        float s = 0.0f;
        #pragma unroll
        for (int k = 0; k < BLOCK / 64; ++k) s += red[k];
        g_out[b] = s + g_hb[0];
    }
}

extern "C" void kernel_launch(void* const* d_in, const int* in_sizes, int n_in,
                              void* d_out, int out_size, void* d_ws, size_t ws_size,
                              hipStream_t stream) {
    const float* sr = (const float*)d_in[0];
    const float* si = (const float*)d_in[1];
    const float* vp = (const float*)d_in[2];
    const float* hw = (const float*)d_in[3];
    const float* hb = (const float*)d_in[4];
    float* out = (float*)d_out;

    dim3 grid(out_size);          // 1024 batch elements, one block each
    dim3 block(BLOCK);
    size_t shmem = (size_t)DIM * sizeof(float2);  // 128 KiB dynamic LDS
    qsim_kernel<<<grid, block, shmem, stream>>>(sr, si, vp, hw, hb, out);
}